// Round 1
// baseline (419.328 us; speedup 1.0000x reference)
//
#include <hip/hip_runtime.h>
#include <math.h>

#define IN_DIM 5
constexpr int B = 8192;
constexpr int N = 100;
constexpr float DT     = 0.01f;
constexpr float MU_DT  = 0.001f;   // MU*dt computed in double then cast, matches ref
constexpr float NU     = 0.2f;
constexpr float SIGMA  = 0.3f;
constexpr float BN_EPS = 1e-5f;
constexpr float FLOORV = 1e-4f;

// ---------------------------------------------------------------------------
// Kernel 1: batch-norm statistics over typeVec (B x 5), training-mode biased
// variance. Writes 20 floats to ws:
//   ws[0..4]  = alpha  (gamma * rsqrt(var+eps))        for bn
//   ws[5..9]  = beta'  (beta - mean*alpha)             for bn
//   ws[10..14]= alphac, ws[15..19] = betac'            for bnc
// ---------------------------------------------------------------------------
__global__ __launch_bounds__(1024) void bn_stats_kernel(
    const float* __restrict__ tv,
    const float* __restrict__ g1, const float* __restrict__ be1,
    const float* __restrict__ g2, const float* __restrict__ be2,
    float* __restrict__ ws)
{
    const int t = threadIdx.x;
    float s[IN_DIM] = {0.f, 0.f, 0.f, 0.f, 0.f};
    float q[IN_DIM] = {0.f, 0.f, 0.f, 0.f, 0.f};
    for (int r = t; r < B; r += 1024) {
        const float* row = tv + r * IN_DIM;
#pragma unroll
        for (int k = 0; k < IN_DIM; ++k) {
            const float v = row[k];
            s[k] += v;
            q[k] += v * v;
        }
    }
#pragma unroll
    for (int k = 0; k < IN_DIM; ++k) {
#pragma unroll
        for (int off = 32; off >= 1; off >>= 1) {
            s[k] += __shfl_xor(s[k], off);
            q[k] += __shfl_xor(q[k], off);
        }
    }
    __shared__ float red[16][2 * IN_DIM];
    const int w = t >> 6, lane = t & 63;
    if (lane == 0) {
#pragma unroll
        for (int k = 0; k < IN_DIM; ++k) {
            red[w][k] = s[k];
            red[w][IN_DIM + k] = q[k];
        }
    }
    __syncthreads();
    if (t == 0) {
#pragma unroll
        for (int k = 0; k < IN_DIM; ++k) {
            float S = 0.f, Q = 0.f;
            for (int u = 0; u < 16; ++u) { S += red[u][k]; Q += red[u][IN_DIM + k]; }
            const float mean = S / (float)B;
            const float var  = Q / (float)B - mean * mean;
            const float inv  = 1.0f / sqrtf(var + BN_EPS);
            const float a1 = inv * g1[k];
            const float a2 = inv * g2[k];
            ws[k]          = a1;
            ws[IN_DIM + k] = be1[k] - mean * a1;
            ws[10 + k]     = a2;
            ws[15 + k]     = be2[k] - mean * a2;
        }
    }
}

// ---------------------------------------------------------------------------
// Kernel 2: the simulation. 1 wave = 4 samples, lane = hidden unit j.
// w2/wc2 columns register-resident; h1 broadcast through per-wave LDS buffer;
// layer-3 via shfl_xor butterfly. No __syncthreads in the whole kernel.
// ---------------------------------------------------------------------------
__global__ __launch_bounds__(256, 2) void sim_kernel(
    const float* __restrict__ bm, const float* __restrict__ cn,
    const float* __restrict__ typeVec,
    const float* __restrict__ mx, const float* __restrict__ mc,
    const float* __restrict__ initial,
    const float* __restrict__ w1, const float* __restrict__ b1,
    const float* __restrict__ w2, const float* __restrict__ b2,
    const float* __restrict__ w3, const float* __restrict__ b3,
    const float* __restrict__ wc1, const float* __restrict__ bc1,
    const float* __restrict__ wc2, const float* __restrict__ bc2,
    const float* __restrict__ wc3, const float* __restrict__ bc3,
    const float* __restrict__ ws, float* __restrict__ out)
{
    const int lane = threadIdx.x & 63;
    const int wid  = threadIdx.x >> 6;
    const int gw   = blockIdx.x * 4 + wid;   // global wave id [0,2048)
    const int b0   = gw * 4;                 // first of 4 samples
    const int j    = lane;                   // hidden unit owned by this lane

    __shared__ float h1buf[4][4][64];        // [wave][sample][unit]

    // --- register-resident layer-2 weight columns (the big cost) ---
    float w2r[64], wc2r[64];
#pragma unroll
    for (int k = 0; k < 64; ++k) {
        w2r[k]  = w2[k * 64 + j];
        wc2r[k] = wc2[k * 64 + j];
    }
    const float w1t = w1[5 * 64 + j], w1x = w1[6 * 64 + j];
    const float w1m = w1[7 * 64 + j], w1c = w1[8 * 64 + j];
    const float wct = wc1[5 * 64 + j], wcx = wc1[6 * 64 + j];
    const float wcm = wc1[7 * 64 + j], wcc = wc1[8 * 64 + j];
    const float b2j = b2[j], bc2j = bc2[j];
    const float w3j = w3[j], wc3j = wc3[j];
    const float b3s = b3[0], bc3s = bc3[0];
    const float x0  = initial[0];

    // --- per-sample layer-1 bases: b1 + bn(typeVec) @ w1[0:5] ---
    float base1[4], basec[4], x[4];
#pragma unroll
    for (int m = 0; m < 4; ++m) {
        const float* tvp = typeVec + (size_t)(b0 + m) * IN_DIM;
        float s1 = b1[j], sc = bc1[j];
#pragma unroll
        for (int k = 0; k < IN_DIM; ++k) {
            const float v   = tvp[k];
            const float bn  = fmaf(v, ws[k], ws[IN_DIM + k]);
            const float bnc = fmaf(v, ws[10 + k], ws[15 + k]);
            s1 = fmaf(bn,  w1[k * 64 + j],  s1);
            sc = fmaf(bnc, wc1[k * 64 + j], sc);
        }
        base1[m] = s1;
        basec[m] = sc;
        x[m] = x0;
    }

    // initial output row: {t=0, x0}
    if (lane < 4) {
        float2* o = (float2*)(out + (size_t)(b0 + lane) * (N + 1) * 2);
        *o = make_float2(0.0f, x0);
    }

    // --- software-pipelined per-step input loads (uniform per sample) ---
    float pbm[4], pcn[4], pmx[4], pmc[4], ccur[4];
#pragma unroll
    for (int m = 0; m < 4; ++m) {
        const size_t b = (size_t)(b0 + m);
        ccur[m] = cn[b * (N + 1)];
        pbm[m]  = bm[b * N];
        pcn[m]  = cn[b * (N + 1) + 1];
        pmx[m]  = mx[b * (N + 1)];
        pmc[m]  = mc[b * N];
    }

    for (int i = 0; i < N; ++i) {
        const float t = (float)i * DT;
        float vbm[4], vdc[4], vmx[4], vmc[4];
#pragma unroll
        for (int m = 0; m < 4; ++m) {
            vbm[m] = pbm[m];
            vdc[m] = pcn[m] - ccur[m];
            ccur[m] = pcn[m];
            vmx[m] = pmx[m];
            vmc[m] = pmc[m];
        }
        if (i + 1 < N) {
#pragma unroll
            for (int m = 0; m < 4; ++m) {
                const size_t b = (size_t)(b0 + m);
                pbm[m] = bm[b * N + i + 1];
                pcn[m] = cn[b * (N + 1) + i + 2];
                pmx[m] = mx[b * (N + 1) + i + 1];
                pmc[m] = mc[b * N + i + 1];
            }
        }

        // ================= pi-MLP =================
#pragma unroll
        for (int m = 0; m < 4; ++m) {
            float h = base1[m];
            h = fmaf(t,      w1t, h);
            h = fmaf(x[m],   w1x, h);
            h = fmaf(vmx[m], w1m, h);
            h = fmaf(vmc[m], w1c, h);
            h1buf[wid][m][j] = fmaxf(h, 0.0f);
        }
        float a0 = b2j, a1 = b2j, a2 = b2j, a3 = b2j;
#pragma unroll
        for (int kk = 0; kk < 16; ++kk) {
            const float4 h0 = *(const float4*)&h1buf[wid][0][kk * 4];
            const float4 h1 = *(const float4*)&h1buf[wid][1][kk * 4];
            const float4 h2 = *(const float4*)&h1buf[wid][2][kk * 4];
            const float4 h3 = *(const float4*)&h1buf[wid][3][kk * 4];
            const float u0 = w2r[kk * 4 + 0], u1 = w2r[kk * 4 + 1];
            const float u2 = w2r[kk * 4 + 2], u3 = w2r[kk * 4 + 3];
            a0 = fmaf(h0.x, u0, a0); a0 = fmaf(h0.y, u1, a0); a0 = fmaf(h0.z, u2, a0); a0 = fmaf(h0.w, u3, a0);
            a1 = fmaf(h1.x, u0, a1); a1 = fmaf(h1.y, u1, a1); a1 = fmaf(h1.z, u2, a1); a1 = fmaf(h1.w, u3, a1);
            a2 = fmaf(h2.x, u0, a2); a2 = fmaf(h2.y, u1, a2); a2 = fmaf(h2.z, u2, a2); a2 = fmaf(h2.w, u3, a2);
            a3 = fmaf(h3.x, u0, a3); a3 = fmaf(h3.y, u1, a3); a3 = fmaf(h3.z, u2, a3); a3 = fmaf(h3.w, u3, a3);
        }
        float p0 = fmaxf(a0, 0.f) * w3j;
        float p1 = fmaxf(a1, 0.f) * w3j;
        float p2 = fmaxf(a2, 0.f) * w3j;
        float p3 = fmaxf(a3, 0.f) * w3j;
#pragma unroll
        for (int s = 32; s >= 1; s >>= 1) {
            p0 += __shfl_xor(p0, s);
            p1 += __shfl_xor(p1, s);
            p2 += __shfl_xor(p2, s);
            p3 += __shfl_xor(p3, s);
        }
        const float opi0 = p0 + b3s, opi1 = p1 + b3s, opi2 = p2 + b3s, opi3 = p3 + b3s;

        // ================= c-MLP =================
#pragma unroll
        for (int m = 0; m < 4; ++m) {
            float h = basec[m];
            h = fmaf(t,      wct, h);
            h = fmaf(x[m],   wcx, h);
            h = fmaf(vmx[m], wcm, h);
            h = fmaf(vmc[m], wcc, h);
            h1buf[wid][m][j] = fmaxf(h, 0.0f);
        }
        float c0 = bc2j, c1 = bc2j, c2 = bc2j, c3 = bc2j;
#pragma unroll
        for (int kk = 0; kk < 16; ++kk) {
            const float4 h0 = *(const float4*)&h1buf[wid][0][kk * 4];
            const float4 h1 = *(const float4*)&h1buf[wid][1][kk * 4];
            const float4 h2 = *(const float4*)&h1buf[wid][2][kk * 4];
            const float4 h3 = *(const float4*)&h1buf[wid][3][kk * 4];
            const float u0 = wc2r[kk * 4 + 0], u1 = wc2r[kk * 4 + 1];
            const float u2 = wc2r[kk * 4 + 2], u3 = wc2r[kk * 4 + 3];
            c0 = fmaf(h0.x, u0, c0); c0 = fmaf(h0.y, u1, c0); c0 = fmaf(h0.z, u2, c0); c0 = fmaf(h0.w, u3, c0);
            c1 = fmaf(h1.x, u0, c1); c1 = fmaf(h1.y, u1, c1); c1 = fmaf(h1.z, u2, c1); c1 = fmaf(h1.w, u3, c1);
            c2 = fmaf(h2.x, u0, c2); c2 = fmaf(h2.y, u1, c2); c2 = fmaf(h2.z, u2, c2); c2 = fmaf(h2.w, u3, c2);
            c3 = fmaf(h3.x, u0, c3); c3 = fmaf(h3.y, u1, c3); c3 = fmaf(h3.z, u2, c3); c3 = fmaf(h3.w, u3, c3);
        }
        float q0 = fmaxf(c0, 0.f) * wc3j;
        float q1 = fmaxf(c1, 0.f) * wc3j;
        float q2 = fmaxf(c2, 0.f) * wc3j;
        float q3 = fmaxf(c3, 0.f) * wc3j;
#pragma unroll
        for (int s = 32; s >= 1; s >>= 1) {
            q0 += __shfl_xor(q0, s);
            q1 += __shfl_xor(q1, s);
            q2 += __shfl_xor(q2, s);
            q3 += __shfl_xor(q3, s);
        }
        const float oc0 = q0 + bc3s, oc1 = q1 + bc3s, oc2 = q2 + bc3s, oc3 = q3 + bc3s;

        // ================= SDE update =================
        const float opi[4] = {opi0, opi1, opi2, opi3};
        const float occ[4] = {oc0, oc1, oc2, oc3};
#pragma unroll
        for (int m = 0; m < 4; ++m) {
            const float drift = MU_DT + fmaf(NU, vbm[m], SIGMA * vdc[m]);
            const float cval  = expf(occ[m]);
            float xn = x[m] + opi[m] * x[m] * drift - cval * x[m] * DT;
            xn = fmaxf(xn - FLOORV, 0.0f) + FLOORV;
            x[m] = xn;
        }

        const float tn = (float)(i + 1) * DT;
        float xs = x[0];
        xs = (lane == 1) ? x[1] : xs;
        xs = (lane == 2) ? x[2] : xs;
        xs = (lane == 3) ? x[3] : xs;
        if (lane < 4) {
            float2* o = (float2*)(out + ((size_t)(b0 + lane) * (N + 1) + (i + 1)) * 2);
            *o = make_float2(tn, xs);
        }
    }
}

extern "C" void kernel_launch(void* const* d_in, const int* in_sizes, int n_in,
                              void* d_out, int out_size, void* d_ws, size_t ws_size,
                              hipStream_t stream) {
    const float* bm        = (const float*)d_in[0];
    const float* cn        = (const float*)d_in[1];
    const float* typeVec   = (const float*)d_in[2];
    const float* mx        = (const float*)d_in[3];
    const float* mc        = (const float*)d_in[4];
    const float* initial   = (const float*)d_in[5];
    const float* bn_gamma  = (const float*)d_in[6];
    const float* bn_beta   = (const float*)d_in[7];
    const float* bnc_gamma = (const float*)d_in[8];
    const float* bnc_beta  = (const float*)d_in[9];
    const float* w1  = (const float*)d_in[10];
    const float* b1  = (const float*)d_in[11];
    const float* w2  = (const float*)d_in[12];
    const float* b2  = (const float*)d_in[13];
    const float* w3  = (const float*)d_in[14];
    const float* b3  = (const float*)d_in[15];
    const float* wc1 = (const float*)d_in[16];
    const float* bc1 = (const float*)d_in[17];
    const float* wc2 = (const float*)d_in[18];
    const float* bc2 = (const float*)d_in[19];
    const float* wc3 = (const float*)d_in[20];
    const float* bc3 = (const float*)d_in[21];
    float* ws  = (float*)d_ws;
    float* out = (float*)d_out;

    bn_stats_kernel<<<1, 1024, 0, stream>>>(typeVec, bn_gamma, bn_beta,
                                            bnc_gamma, bnc_beta, ws);
    sim_kernel<<<512, 256, 0, stream>>>(bm, cn, typeVec, mx, mc, initial,
                                        w1, b1, w2, b2, w3, b3,
                                        wc1, bc1, wc2, bc2, wc3, bc3,
                                        ws, out);
}

// Round 2
// 238.246 us; speedup vs baseline: 1.7601x; 1.7601x over previous
//
#include <hip/hip_runtime.h>
#include <math.h>

#define IN_DIM 5
constexpr int B = 8192;
constexpr int N = 100;
constexpr float DT     = 0.01f;
constexpr float MU_DT  = 0.001f;
constexpr float NU     = 0.2f;
constexpr float SIGMA  = 0.3f;
constexpr float BN_EPS = 1e-5f;
constexpr float FLOORV = 1e-4f;

typedef __attribute__((ext_vector_type(8))) short short8;
typedef __attribute__((ext_vector_type(4))) float f32x4;

// truncation-based bf16 split: h = hi + lo with |err| ~ 2^-16 |h|
__device__ __forceinline__ void bf16_split(float h, short& hi, short& lo) {
    unsigned int ub = __builtin_bit_cast(unsigned int, h);
    hi = (short)(ub >> 16);
    float hif = __builtin_bit_cast(float, ub & 0xffff0000u);
    float l = h - hif;
    lo = (short)(__builtin_bit_cast(unsigned int, l) >> 16);
}

// ---------------------------------------------------------------------------
// Kernel 1: batch-norm stats (unchanged from R1 — passed, ~µs).
// ws[0..4]=alpha, ws[5..9]=beta', ws[10..14]=alphac, ws[15..19]=betac'
// ---------------------------------------------------------------------------
__global__ __launch_bounds__(1024) void bn_stats_kernel(
    const float* __restrict__ tv,
    const float* __restrict__ g1, const float* __restrict__ be1,
    const float* __restrict__ g2, const float* __restrict__ be2,
    float* __restrict__ ws)
{
    const int t = threadIdx.x;
    float s[IN_DIM] = {0.f, 0.f, 0.f, 0.f, 0.f};
    float q[IN_DIM] = {0.f, 0.f, 0.f, 0.f, 0.f};
    for (int r = t; r < B; r += 1024) {
        const float* row = tv + r * IN_DIM;
#pragma unroll
        for (int k = 0; k < IN_DIM; ++k) {
            const float v = row[k];
            s[k] += v;
            q[k] += v * v;
        }
    }
#pragma unroll
    for (int k = 0; k < IN_DIM; ++k) {
#pragma unroll
        for (int off = 32; off >= 1; off >>= 1) {
            s[k] += __shfl_xor(s[k], off);
            q[k] += __shfl_xor(q[k], off);
        }
    }
    __shared__ float red[16][2 * IN_DIM];
    const int w = t >> 6, lane = t & 63;
    if (lane == 0) {
#pragma unroll
        for (int k = 0; k < IN_DIM; ++k) {
            red[w][k] = s[k];
            red[w][IN_DIM + k] = q[k];
        }
    }
    __syncthreads();
    if (t == 0) {
#pragma unroll
        for (int k = 0; k < IN_DIM; ++k) {
            float S = 0.f, Q = 0.f;
            for (int u = 0; u < 16; ++u) { S += red[u][k]; Q += red[u][IN_DIM + k]; }
            const float mean = S / (float)B;
            const float var  = Q / (float)B - mean * mean;
            const float inv  = 1.0f / sqrtf(var + BN_EPS);
            const float a1 = inv * g1[k];
            const float a2 = inv * g2[k];
            ws[k]          = a1;
            ws[IN_DIM + k] = be1[k] - mean * a1;
            ws[10 + k]     = a2;
            ws[15 + k]     = be2[k] - mean * a2;
        }
    }
}

// ---------------------------------------------------------------------------
// Kernel 2: simulation via MFMA. 1 wave = 1 block = 16 samples.
// Layer-2 (the 4096-MAC matvec) = mfma_f32_16x16x32_bf16 with hi/lo split.
// Lane l: sample s = l&15, hidden-unit octets g*8.. / 32+g*8.. (g = l>>4).
// Weight B-fragments (hi+lo, both MLPs) staged once in LDS; 32 ds_read_b128
// per step instead of 128 uniform broadcasts. No barriers anywhere.
// ---------------------------------------------------------------------------
__global__ __launch_bounds__(64, 1) void sim_kernel(
    const float* __restrict__ bm, const float* __restrict__ cn,
    const float* __restrict__ typeVec,
    const float* __restrict__ mx, const float* __restrict__ mc,
    const float* __restrict__ initial,
    const float* __restrict__ w1, const float* __restrict__ b1,
    const float* __restrict__ w2, const float* __restrict__ b2,
    const float* __restrict__ w3, const float* __restrict__ b3,
    const float* __restrict__ wc1, const float* __restrict__ bc1,
    const float* __restrict__ wc2, const float* __restrict__ bc2,
    const float* __restrict__ wc3, const float* __restrict__ bc3,
    const float* __restrict__ ws, float* __restrict__ out)
{
    const int l  = threadIdx.x;      // 0..63
    const int s  = l & 15;           // sample within wave
    const int g  = l >> 4;           // k-octet group
    const int b0 = blockIdx.x * 16;  // first sample of this wave

    // LDS: B-fragments for layer-2 weights. slot = mlp*16 + (kt*4+nt)*2 + prec
    __shared__ short8 BF[32][64];

    // ---- stage layer-2 weight fragments (once) ----
#pragma unroll
    for (int mlp = 0; mlp < 2; ++mlp) {
        const float* W = mlp ? wc2 : w2;
#pragma unroll
        for (int kt = 0; kt < 2; ++kt) {
#pragma unroll
            for (int nt = 0; nt < 4; ++nt) {
                short8 fh, fl;
#pragma unroll
                for (int e = 0; e < 8; ++e) {
                    const int k = 32 * kt + g * 8 + e;
                    const int n = 16 * nt + s;
                    short hi, lo;
                    bf16_split(W[k * 64 + n], hi, lo);
                    fh[e] = hi; fl[e] = lo;
                }
                const int slot = mlp * 16 + (kt * 4 + nt) * 2;
                BF[slot][l]     = fh;
                BF[slot + 1][l] = fl;
            }
        }
    }

    // ---- per-lane layer-1 constants: 16 units each for both MLPs ----
    float bnv[IN_DIM], bncv[IN_DIM];
    {
        const float* tvp = typeVec + (size_t)(b0 + s) * IN_DIM;
#pragma unroll
        for (int k = 0; k < IN_DIM; ++k) {
            const float v = tvp[k];
            bnv[k]  = fmaf(v, ws[k],      ws[IN_DIM + k]);
            bncv[k] = fmaf(v, ws[10 + k], ws[15 + k]);
        }
    }
    float wtA[16], wxA[16], wmA[16], wcAr[16], bsA[16];
    float wtB[16], wxB[16], wmB[16], wcBr[16], bsB[16];
#pragma unroll
    for (int j = 0; j < 16; ++j) {
        const int u = (j < 8) ? (g * 8 + j) : (32 + g * 8 + (j - 8));
        wtA[j] = w1[5 * 64 + u]; wxA[j] = w1[6 * 64 + u];
        wmA[j] = w1[7 * 64 + u]; wcAr[j] = w1[8 * 64 + u];
        float a = b1[u];
#pragma unroll
        for (int k = 0; k < IN_DIM; ++k) a = fmaf(bnv[k], w1[k * 64 + u], a);
        bsA[j] = a;
        wtB[j] = wc1[5 * 64 + u]; wxB[j] = wc1[6 * 64 + u];
        wmB[j] = wc1[7 * 64 + u]; wcBr[j] = wc1[8 * 64 + u];
        float c = bc1[u];
#pragma unroll
        for (int k = 0; k < IN_DIM; ++k) c = fmaf(bncv[k], wc1[k * 64 + u], c);
        bsB[j] = c;
    }
    float b2A[4], b2B[4], w3A[4], w3B[4];
#pragma unroll
    for (int nt = 0; nt < 4; ++nt) {
        b2A[nt] = b2[16 * nt + s];  b2B[nt] = bc2[16 * nt + s];
        w3A[nt] = w3[16 * nt + s];  w3B[nt] = wc3[16 * nt + s];
    }
    const float b3s = b3[0], bc3s = bc3[0];
    const float x0  = initial[0];

    // ---- per-lane input pointers (sample s) & prefetch ----
    const float* bmp = bm + (size_t)(b0 + s) * N;
    const float* cnp = cn + (size_t)(b0 + s) * (N + 1);
    const float* mxp = mx + (size_t)(b0 + s) * (N + 1);
    const float* mcp = mc + (size_t)(b0 + s) * N;
    float ccur = cnp[0];
    float pbm = bmp[0], pcn = cnp[1], pmx = mxp[0], pmc = mcp[0];

    float x = x0;
    float2* op = (float2*)(out + (size_t)(b0 + l) * (N + 1) * 2);
    if (l < 16) op[0] = make_float2(0.0f, x0);

    const int src = ((s >> 2) << 4) | (s & 3);   // bpermute source lane

    for (int i = 0; i < N; ++i) {
        const float t = (float)i * DT;
        const float vbm = pbm, vdc = pcn - ccur, vmx = pmx, vmc = pmc;
        ccur = pcn;
        if (i + 1 < N) {
            pbm = bmp[i + 1]; pcn = cnp[i + 2];
            pmx = mxp[i + 1]; pmc = mcp[i + 1];
        }

        float p0, p1, p2, p3;   // pi head partials
        float q0, q1, q2, q3;   // c  head partials

#pragma unroll
        for (int mlp = 0; mlp < 2; ++mlp) {
            // layer-1: 16 units in-lane, f32, then split to A-fragments
            short8 ah0, ah1, al0, al1;
#pragma unroll
            for (int j = 0; j < 16; ++j) {
                float h = mlp ? bsB[j] : bsA[j];
                h = fmaf(t,   mlp ? wtB[j] : wtA[j], h);
                h = fmaf(x,   mlp ? wxB[j] : wxA[j], h);
                h = fmaf(vmx, mlp ? wmB[j] : wmA[j], h);
                h = fmaf(vmc, mlp ? wcBr[j] : wcAr[j], h);
                h = fmaxf(h, 0.0f);
                short hi, lo;
                bf16_split(h, hi, lo);
                if (j < 8) { ah0[j] = hi; al0[j] = lo; }
                else       { ah1[j - 8] = hi; al1[j - 8] = lo; }
            }
            // layer-2 via MFMA, bias in C-init
            f32x4 acc[4];
#pragma unroll
            for (int nt = 0; nt < 4; ++nt) {
                const float bb = mlp ? b2B[nt] : b2A[nt];
                acc[nt] = (f32x4){bb, bb, bb, bb};
            }
#pragma unroll
            for (int kt = 0; kt < 2; ++kt) {
                const short8 a_h = kt ? ah1 : ah0;
                const short8 a_l = kt ? al1 : al0;
#pragma unroll
                for (int nt = 0; nt < 4; ++nt) {
                    const int slot = mlp * 16 + (kt * 4 + nt) * 2;
                    const short8 bh = BF[slot][l];
                    const short8 bl = BF[slot + 1][l];
                    acc[nt] = __builtin_amdgcn_mfma_f32_16x16x32_bf16(a_h, bh, acc[nt], 0, 0, 0);
                    acc[nt] = __builtin_amdgcn_mfma_f32_16x16x32_bf16(a_l, bh, acc[nt], 0, 0, 0);
                    acc[nt] = __builtin_amdgcn_mfma_f32_16x16x32_bf16(a_h, bl, acc[nt], 0, 0, 0);
                }
            }
            // layer-3: relu * w3, reduce over n (16 lanes within group)
            float r0 = 0.f, r1 = 0.f, r2 = 0.f, r3 = 0.f;
#pragma unroll
            for (int nt = 0; nt < 4; ++nt) {
                const float w3n = mlp ? w3B[nt] : w3A[nt];
                r0 = fmaf(fmaxf(acc[nt][0], 0.f), w3n, r0);
                r1 = fmaf(fmaxf(acc[nt][1], 0.f), w3n, r1);
                r2 = fmaf(fmaxf(acc[nt][2], 0.f), w3n, r2);
                r3 = fmaf(fmaxf(acc[nt][3], 0.f), w3n, r3);
            }
#pragma unroll
            for (int off = 1; off <= 8; off <<= 1) {
                r0 += __shfl_xor(r0, off);
                r1 += __shfl_xor(r1, off);
                r2 += __shfl_xor(r2, off);
                r3 += __shfl_xor(r3, off);
            }
            if (mlp == 0) { p0 = r0 + b3s; p1 = r1 + b3s; p2 = r2 + b3s; p3 = r3 + b3s; }
            else          { q0 = r0 + bc3s; q1 = r1 + bc3s; q2 = r2 + bc3s; q3 = r3 + bc3s; }
        }

        // distribute pi[s], clogit[s] to lane-owns-sample layout
        float sp = (l & 1) ? p1 : p0;
        float sp2 = (l & 1) ? p3 : p2;
        sp = (l & 2) ? sp2 : sp;
        float sq = (l & 1) ? q1 : q0;
        float sq2 = (l & 1) ? q3 : q2;
        sq = (l & 2) ? sq2 : sq;
        const float pi_l = __shfl(sp, src);
        const float cl_l = __shfl(sq, src);
        const float c_l  = expf(cl_l);

        // SDE update (per lane, sample s; redundant across the 4 groups)
        const float drift = MU_DT + fmaf(NU, vbm, SIGMA * vdc);
        float xn = x + pi_l * x * drift - c_l * x * DT;
        xn = fmaxf(xn - FLOORV, 0.0f) + FLOORV;
        x = xn;

        if (l < 16) op[i + 1] = make_float2((float)(i + 1) * DT, x);
    }
}

extern "C" void kernel_launch(void* const* d_in, const int* in_sizes, int n_in,
                              void* d_out, int out_size, void* d_ws, size_t ws_size,
                              hipStream_t stream) {
    const float* bm        = (const float*)d_in[0];
    const float* cn        = (const float*)d_in[1];
    const float* typeVec   = (const float*)d_in[2];
    const float* mx        = (const float*)d_in[3];
    const float* mc        = (const float*)d_in[4];
    const float* initial   = (const float*)d_in[5];
    const float* bn_gamma  = (const float*)d_in[6];
    const float* bn_beta   = (const float*)d_in[7];
    const float* bnc_gamma = (const float*)d_in[8];
    const float* bnc_beta  = (const float*)d_in[9];
    const float* w1  = (const float*)d_in[10];
    const float* b1  = (const float*)d_in[11];
    const float* w2  = (const float*)d_in[12];
    const float* b2  = (const float*)d_in[13];
    const float* w3  = (const float*)d_in[14];
    const float* b3  = (const float*)d_in[15];
    const float* wc1 = (const float*)d_in[16];
    const float* bc1 = (const float*)d_in[17];
    const float* wc2 = (const float*)d_in[18];
    const float* bc2 = (const float*)d_in[19];
    const float* wc3 = (const float*)d_in[20];
    const float* bc3 = (const float*)d_in[21];
    float* wsp = (float*)d_ws;
    float* out = (float*)d_out;

    bn_stats_kernel<<<1, 1024, 0, stream>>>(typeVec, bn_gamma, bn_beta,
                                            bnc_gamma, bnc_beta, wsp);
    sim_kernel<<<512, 64, 0, stream>>>(bm, cn, typeVec, mx, mc, initial,
                                       w1, b1, w2, b2, w3, b3,
                                       wc1, bc1, wc2, bc2, wc3, bc3,
                                       wsp, out);
}

// Round 3
// 98.234 us; speedup vs baseline: 4.2687x; 2.4253x over previous
//
#include <hip/hip_runtime.h>
#include <math.h>

#define IN_DIM 5
constexpr int B = 8192;
constexpr int N = 100;
constexpr float DT     = 0.01f;
constexpr float MU_DT  = 0.001f;
constexpr float NU     = 0.2f;
constexpr float SIGMA  = 0.3f;
constexpr float BN_EPS = 1e-5f;
constexpr float FLOORV = 1e-4f;

typedef __attribute__((ext_vector_type(8))) short short8;
typedef __attribute__((ext_vector_type(4))) float f32x4;

// truncation-based bf16 split: h = hi + lo with |err| ~ 2^-16 |h|
__device__ __forceinline__ void bf16_split(float h, short& hi, short& lo) {
    unsigned int ub = __builtin_bit_cast(unsigned int, h);
    hi = (short)(ub >> 16);
    float hif = __builtin_bit_cast(float, ub & 0xffff0000u);
    float l = h - hif;
    lo = (short)(__builtin_bit_cast(unsigned int, l) >> 16);
}

// sum over each aligned 16-lane group, all via VALU DPP (no DS pipe):
// xor1 (quad_perm [1,0,3,2]), xor2 (quad_perm [2,3,0,1]),
// row_half_mirror (0x141), row_mirror (0x140). Result uniform in group.
__device__ __forceinline__ float red16(float v) {
#if __has_builtin(__builtin_amdgcn_update_dpp)
    int x;
    x = __builtin_amdgcn_update_dpp(0, __builtin_bit_cast(int, v), 0xB1, 0xF, 0xF, false);
    v += __builtin_bit_cast(float, x);
    x = __builtin_amdgcn_update_dpp(0, __builtin_bit_cast(int, v), 0x4E, 0xF, 0xF, false);
    v += __builtin_bit_cast(float, x);
    x = __builtin_amdgcn_update_dpp(0, __builtin_bit_cast(int, v), 0x141, 0xF, 0xF, false);
    v += __builtin_bit_cast(float, x);
    x = __builtin_amdgcn_update_dpp(0, __builtin_bit_cast(int, v), 0x140, 0xF, 0xF, false);
    v += __builtin_bit_cast(float, x);
    return v;
#else
    v += __shfl_xor(v, 1);
    v += __shfl_xor(v, 2);
    v += __shfl_xor(v, 4);
    v += __shfl_xor(v, 8);
    return v;
#endif
}

// ---------------------------------------------------------------------------
// Kernel 1: batch-norm stats (unchanged — correct & tiny).
// ws[0..4]=alpha, ws[5..9]=beta', ws[10..14]=alphac, ws[15..19]=betac'
// ---------------------------------------------------------------------------
__global__ __launch_bounds__(1024) void bn_stats_kernel(
    const float* __restrict__ tv,
    const float* __restrict__ g1, const float* __restrict__ be1,
    const float* __restrict__ g2, const float* __restrict__ be2,
    float* __restrict__ ws)
{
    const int t = threadIdx.x;
    float s[IN_DIM] = {0.f, 0.f, 0.f, 0.f, 0.f};
    float q[IN_DIM] = {0.f, 0.f, 0.f, 0.f, 0.f};
    for (int r = t; r < B; r += 1024) {
        const float* row = tv + r * IN_DIM;
#pragma unroll
        for (int k = 0; k < IN_DIM; ++k) {
            const float v = row[k];
            s[k] += v;
            q[k] += v * v;
        }
    }
#pragma unroll
    for (int k = 0; k < IN_DIM; ++k) {
#pragma unroll
        for (int off = 32; off >= 1; off >>= 1) {
            s[k] += __shfl_xor(s[k], off);
            q[k] += __shfl_xor(q[k], off);
        }
    }
    __shared__ float red[16][2 * IN_DIM];
    const int w = t >> 6, lane = t & 63;
    if (lane == 0) {
#pragma unroll
        for (int k = 0; k < IN_DIM; ++k) {
            red[w][k] = s[k];
            red[w][IN_DIM + k] = q[k];
        }
    }
    __syncthreads();
    if (t == 0) {
#pragma unroll
        for (int k = 0; k < IN_DIM; ++k) {
            float S = 0.f, Q = 0.f;
            for (int u = 0; u < 16; ++u) { S += red[u][k]; Q += red[u][IN_DIM + k]; }
            const float mean = S / (float)B;
            const float var  = Q / (float)B - mean * mean;
            const float inv  = 1.0f / sqrtf(var + BN_EPS);
            const float a1 = inv * g1[k];
            const float a2 = inv * g2[k];
            ws[k]          = a1;
            ws[IN_DIM + k] = be1[k] - mean * a1;
            ws[10 + k]     = a2;
            ws[15 + k]     = be2[k] - mean * a2;
        }
    }
}

// ---------------------------------------------------------------------------
// Kernel 2: simulation. Block = 128 thr = 2 waves over the SAME 16 samples:
// wave 0 computes the pi-MLP, wave 1 the c-MLP (halves the per-step chain).
// All weights (B-fragments + layer-1 columns) register-resident — no per-step
// weight LDS reads. Layer-3 reduce via DPP (VALU, no DS pipe). pi/c exchanged
// through a 256-B double-buffered LDS slot, one __syncthreads per step; both
// waves then redundantly compute the SDE update so x stays in-register.
// ---------------------------------------------------------------------------
__global__ __launch_bounds__(128, 1) void sim_kernel(
    const float* __restrict__ bm, const float* __restrict__ cn,
    const float* __restrict__ typeVec,
    const float* __restrict__ mx, const float* __restrict__ mc,
    const float* __restrict__ initial,
    const float* __restrict__ w1, const float* __restrict__ b1,
    const float* __restrict__ w2, const float* __restrict__ b2,
    const float* __restrict__ w3, const float* __restrict__ b3,
    const float* __restrict__ wc1, const float* __restrict__ bc1,
    const float* __restrict__ wc2, const float* __restrict__ bc2,
    const float* __restrict__ wc3, const float* __restrict__ bc3,
    const float* __restrict__ ws, float* __restrict__ out)
{
    const int tid = threadIdx.x;
    const int wid = tid >> 6;        // 0 = pi-MLP, 1 = c-MLP
    const int l   = tid & 63;
    const int s   = l & 15;          // sample within block's group of 16
    const int g   = l >> 4;          // k/row sub-group
    const int b0  = blockIdx.x * 16;

    __shared__ float ex[2][16][2];   // [buf][sample][{pi, c_logit}]

    // this wave's MLP parameter set
    const float* W1 = wid ? wc1 : w1;
    const float* B1 = wid ? bc1 : b1;
    const float* W2 = wid ? wc2 : w2;
    const float* B2 = wid ? bc2 : b2;
    const float* W3 = wid ? wc3 : w3;
    const float* B3 = wid ? bc3 : b3;
    const float* alpha = ws + (wid ? 10 : 0);
    const float* beta  = ws + (wid ? 15 : 5);

    // ---- register-resident B-fragments of W2 (hi/lo split) ----
    short8 Bh[2][4], Bl[2][4];
#pragma unroll
    for (int kt = 0; kt < 2; ++kt) {
#pragma unroll
        for (int nt = 0; nt < 4; ++nt) {
            short8 fh, fl;
#pragma unroll
            for (int e = 0; e < 8; ++e) {
                short hi, lo;
                bf16_split(W2[(32 * kt + 8 * g + e) * 64 + 16 * nt + s], hi, lo);
                fh[e] = hi; fl[e] = lo;
            }
            Bh[kt][nt] = fh; Bl[kt][nt] = fl;
        }
    }

    // ---- bn affine of this lane's sample, then layer-1 constants ----
    float bnv[IN_DIM];
    {
        const float* tvp = typeVec + (size_t)(b0 + s) * IN_DIM;
#pragma unroll
        for (int k = 0; k < IN_DIM; ++k)
            bnv[k] = fmaf(tvp[k], alpha[k], beta[k]);
    }
    float bs[16], wt[16], wx[16], wm[16], wcr[16];
#pragma unroll
    for (int j = 0; j < 16; ++j) {
        const int u = (j < 8) ? (g * 8 + j) : (32 + g * 8 + (j - 8));
        wt[j]  = W1[5 * 64 + u];
        wx[j]  = W1[6 * 64 + u];
        wm[j]  = W1[7 * 64 + u];
        wcr[j] = W1[8 * 64 + u];
        float a = B1[u];
#pragma unroll
        for (int k = 0; k < IN_DIM; ++k) a = fmaf(bnv[k], W1[k * 64 + u], a);
        bs[j] = a;
    }
    float b2v[4], w3v[4];
#pragma unroll
    for (int nt = 0; nt < 4; ++nt) {
        b2v[nt] = B2[16 * nt + s];
        w3v[nt] = W3[16 * nt + s];
    }
    const float b3s = B3[0];
    const float x0  = initial[0];

    // ---- per-lane inputs (sample s) with one-step prefetch ----
    const float* bmp = bm + (size_t)(b0 + s) * N;
    const float* cnp = cn + (size_t)(b0 + s) * (N + 1);
    const float* mxp = mx + (size_t)(b0 + s) * (N + 1);
    const float* mcp = mc + (size_t)(b0 + s) * N;
    float ccur = cnp[0];
    float pbm = bmp[0], pcn = cnp[1], pmx = mxp[0], pmc = mcp[0];

    float x = x0;
    float* outp = out + (size_t)(b0 + s) * (N + 1) * 2;
    if (tid < 16) ((float2*)outp)[0] = make_float2(0.0f, x0);

    for (int i = 0; i < N; ++i) {
        const float t = (float)i * DT;
        const float vbm = pbm, vdc = pcn - ccur, vmx = pmx, vmc = pmc;
        ccur = pcn;
        if (i + 1 < N) {
            pbm = bmp[i + 1]; pcn = cnp[i + 2];
            pmx = mxp[i + 1]; pmc = mcp[i + 1];
        }

        // ---- layer-1 (16 units in-lane), relu, hi/lo split to A-frags ----
        short8 ah0, ah1, al0, al1;
#pragma unroll
        for (int j = 0; j < 16; ++j) {
            float h = bs[j];
            h = fmaf(t,   wt[j],  h);
            h = fmaf(x,   wx[j],  h);
            h = fmaf(vmx, wm[j],  h);
            h = fmaf(vmc, wcr[j], h);
            h = fmaxf(h, 0.0f);
            short hi, lo;
            bf16_split(h, hi, lo);
            if (j < 8) { ah0[j] = hi; al0[j] = lo; }
            else       { ah1[j - 8] = hi; al1[j - 8] = lo; }
        }

        // ---- layer-2 MFMA (bias in C-init), 3-term hi/lo product ----
        f32x4 acc[4];
#pragma unroll
        for (int nt = 0; nt < 4; ++nt)
            acc[nt] = (f32x4){b2v[nt], b2v[nt], b2v[nt], b2v[nt]};
#pragma unroll
        for (int kt = 0; kt < 2; ++kt) {
            const short8 a_h = kt ? ah1 : ah0;
            const short8 a_l = kt ? al1 : al0;
#pragma unroll
            for (int nt = 0; nt < 4; ++nt) {
                acc[nt] = __builtin_amdgcn_mfma_f32_16x16x32_bf16(a_h, Bh[kt][nt], acc[nt], 0, 0, 0);
                acc[nt] = __builtin_amdgcn_mfma_f32_16x16x32_bf16(a_l, Bh[kt][nt], acc[nt], 0, 0, 0);
                acc[nt] = __builtin_amdgcn_mfma_f32_16x16x32_bf16(a_h, Bl[kt][nt], acc[nt], 0, 0, 0);
            }
        }

        // ---- layer-3: relu * w3, DPP-reduce over the 16 n-lanes ----
        float r0 = 0.f, r1 = 0.f, r2 = 0.f, r3 = 0.f;
#pragma unroll
        for (int nt = 0; nt < 4; ++nt) {
            r0 = fmaf(fmaxf(acc[nt][0], 0.f), w3v[nt], r0);
            r1 = fmaf(fmaxf(acc[nt][1], 0.f), w3v[nt], r1);
            r2 = fmaf(fmaxf(acc[nt][2], 0.f), w3v[nt], r2);
            r3 = fmaf(fmaxf(acc[nt][3], 0.f), w3v[nt], r3);
        }
        r0 = red16(r0); r1 = red16(r1); r2 = red16(r2); r3 = red16(r3);

        // lane 16g+r (r<4) owns sample 4g+r; publish this wave's head output
        const int r4 = l & 15;
        float wv = r0;
        wv = (r4 == 1) ? r1 : wv;
        wv = (r4 == 2) ? r2 : wv;
        wv = (r4 == 3) ? r3 : wv;
        if (r4 < 4) ex[i & 1][4 * g + r4][wid] = wv + b3s;
        __syncthreads();

        // ---- SDE update (redundant in both waves; x stays in-register) ----
        const float2 pc = *(const float2*)&ex[i & 1][s][0];
        const float pi_v = pc.x;
        const float c_v  = expf(pc.y);
        const float drift = MU_DT + fmaf(NU, vbm, SIGMA * vdc);
        float xn = x + pi_v * x * drift - c_v * x * DT;
        xn = fmaxf(xn - FLOORV, 0.0f) + FLOORV;
        x = xn;

        if (tid < 16) ((float2*)outp)[i + 1] = make_float2((float)(i + 1) * DT, x);
    }
}

extern "C" void kernel_launch(void* const* d_in, const int* in_sizes, int n_in,
                              void* d_out, int out_size, void* d_ws, size_t ws_size,
                              hipStream_t stream) {
    const float* bm        = (const float*)d_in[0];
    const float* cn        = (const float*)d_in[1];
    const float* typeVec   = (const float*)d_in[2];
    const float* mx        = (const float*)d_in[3];
    const float* mc        = (const float*)d_in[4];
    const float* initial   = (const float*)d_in[5];
    const float* bn_gamma  = (const float*)d_in[6];
    const float* bn_beta   = (const float*)d_in[7];
    const float* bnc_gamma = (const float*)d_in[8];
    const float* bnc_beta  = (const float*)d_in[9];
    const float* w1  = (const float*)d_in[10];
    const float* b1  = (const float*)d_in[11];
    const float* w2  = (const float*)d_in[12];
    const float* b2  = (const float*)d_in[13];
    const float* w3  = (const float*)d_in[14];
    const float* b3  = (const float*)d_in[15];
    const float* wc1 = (const float*)d_in[16];
    const float* bc1 = (const float*)d_in[17];
    const float* wc2 = (const float*)d_in[18];
    const float* bc2 = (const float*)d_in[19];
    const float* wc3 = (const float*)d_in[20];
    const float* bc3 = (const float*)d_in[21];
    float* wsp = (float*)d_ws;
    float* out = (float*)d_out;

    bn_stats_kernel<<<1, 1024, 0, stream>>>(typeVec, bn_gamma, bn_beta,
                                            bnc_gamma, bnc_beta, wsp);
    sim_kernel<<<512, 128, 0, stream>>>(bm, cn, typeVec, mx, mc, initial,
                                        w1, b1, w2, b2, w3, b3,
                                        wc1, bc1, wc2, bc2, wc3, bc3,
                                        wsp, out);
}

// Round 4
// 97.387 us; speedup vs baseline: 4.3058x; 1.0087x over previous
//
#include <hip/hip_runtime.h>
#include <math.h>

#define IN_DIM 5
constexpr int B = 8192;
constexpr int N = 100;
constexpr float DT     = 0.01f;
constexpr float MU_DT  = 0.001f;
constexpr float NU     = 0.2f;
constexpr float SIGMA  = 0.3f;
constexpr float BN_EPS = 1e-5f;
constexpr float FLOORV = 1e-4f;

typedef __attribute__((ext_vector_type(8))) short short8;
typedef __attribute__((ext_vector_type(4))) float f32x4;

// truncation-based bf16 split: h = hi + lo with |err| ~ 2^-16 |h|
__device__ __forceinline__ void bf16_split(float h, short& hi, short& lo) {
    unsigned int ub = __builtin_bit_cast(unsigned int, h);
    hi = (short)(ub >> 16);
    float hif = __builtin_bit_cast(float, ub & 0xffff0000u);
    float l = h - hif;
    lo = (short)(__builtin_bit_cast(unsigned int, l) >> 16);
}

// sum over each aligned 16-lane group via DPP (VALU only, no DS pipe)
__device__ __forceinline__ float red16(float v) {
#if __has_builtin(__builtin_amdgcn_update_dpp)
    int x;
    x = __builtin_amdgcn_update_dpp(0, __builtin_bit_cast(int, v), 0xB1, 0xF, 0xF, false);
    v += __builtin_bit_cast(float, x);
    x = __builtin_amdgcn_update_dpp(0, __builtin_bit_cast(int, v), 0x4E, 0xF, 0xF, false);
    v += __builtin_bit_cast(float, x);
    x = __builtin_amdgcn_update_dpp(0, __builtin_bit_cast(int, v), 0x141, 0xF, 0xF, false);
    v += __builtin_bit_cast(float, x);
    x = __builtin_amdgcn_update_dpp(0, __builtin_bit_cast(int, v), 0x140, 0xF, 0xF, false);
    v += __builtin_bit_cast(float, x);
    return v;
#else
    v += __shfl_xor(v, 1);
    v += __shfl_xor(v, 2);
    v += __shfl_xor(v, 4);
    v += __shfl_xor(v, 8);
    return v;
#endif
}

// ---------------------------------------------------------------------------
// Kernel 1: batch-norm stats (unchanged).
// ws[0..4]=alpha, ws[5..9]=beta', ws[10..14]=alphac, ws[15..19]=betac'
// ---------------------------------------------------------------------------
__global__ __launch_bounds__(1024) void bn_stats_kernel(
    const float* __restrict__ tv,
    const float* __restrict__ g1, const float* __restrict__ be1,
    const float* __restrict__ g2, const float* __restrict__ be2,
    float* __restrict__ ws)
{
    const int t = threadIdx.x;
    float s[IN_DIM] = {0.f, 0.f, 0.f, 0.f, 0.f};
    float q[IN_DIM] = {0.f, 0.f, 0.f, 0.f, 0.f};
    for (int r = t; r < B; r += 1024) {
        const float* row = tv + r * IN_DIM;
#pragma unroll
        for (int k = 0; k < IN_DIM; ++k) {
            const float v = row[k];
            s[k] += v;
            q[k] += v * v;
        }
    }
#pragma unroll
    for (int k = 0; k < IN_DIM; ++k) {
#pragma unroll
        for (int off = 32; off >= 1; off >>= 1) {
            s[k] += __shfl_xor(s[k], off);
            q[k] += __shfl_xor(q[k], off);
        }
    }
    __shared__ float red[16][2 * IN_DIM];
    const int w = t >> 6, lane = t & 63;
    if (lane == 0) {
#pragma unroll
        for (int k = 0; k < IN_DIM; ++k) {
            red[w][k] = s[k];
            red[w][IN_DIM + k] = q[k];
        }
    }
    __syncthreads();
    if (t == 0) {
#pragma unroll
        for (int k = 0; k < IN_DIM; ++k) {
            float S = 0.f, Q = 0.f;
            for (int u = 0; u < 16; ++u) { S += red[u][k]; Q += red[u][IN_DIM + k]; }
            const float mean = S / (float)B;
            const float var  = Q / (float)B - mean * mean;
            const float inv  = 1.0f / sqrtf(var + BN_EPS);
            const float a1 = inv * g1[k];
            const float a2 = inv * g2[k];
            ws[k]          = a1;
            ws[IN_DIM + k] = be1[k] - mean * a1;
            ws[10 + k]     = a2;
            ws[15 + k]     = be2[k] - mean * a2;
        }
    }
}

// ---------------------------------------------------------------------------
// Kernel 2: simulation. Block = 256 thr = 4 waves over the SAME 16 samples.
// wave w: mlp = w&1 (pi / c), half = w>>1 (nt columns {2h, 2h+1}).
// Layer-1 duplicated per half (cheap VALU); MFMA work split 4 ways; partial
// head outputs merged through a float4/sample LDS slot, 1 barrier/step.
// All per-step inputs pre-staged in LDS (coalesced); trajectory kept in LDS
// and written coalesced in the epilogue — zero global ops inside the loop.
// ---------------------------------------------------------------------------
__global__ __launch_bounds__(256, 2) void sim_kernel(
    const float* __restrict__ bm, const float* __restrict__ cn,
    const float* __restrict__ typeVec,
    const float* __restrict__ mx, const float* __restrict__ mc,
    const float* __restrict__ initial,
    const float* __restrict__ w1, const float* __restrict__ b1,
    const float* __restrict__ w2, const float* __restrict__ b2,
    const float* __restrict__ w3, const float* __restrict__ b3,
    const float* __restrict__ wc1, const float* __restrict__ bc1,
    const float* __restrict__ wc2, const float* __restrict__ bc2,
    const float* __restrict__ wc3, const float* __restrict__ bc3,
    const float* __restrict__ ws, float* __restrict__ out)
{
    const int tid  = threadIdx.x;
    const int wid  = tid >> 6;       // 0..3
    const int l    = tid & 63;
    const int s    = l & 15;         // sample (A-row) / unit (B-col) index
    const int g    = l >> 4;         // k-octet / D-row group
    const int mlp  = wid & 1;        // 0 = pi-MLP, 1 = c-MLP
    const int half = wid >> 1;       // nt half: columns {2*half, 2*half+1}
    const int b0   = blockIdx.x * 16;

    __shared__ float4 SI[N][16];     // [step][sample] = {bm, dcn, mx, mc}
    __shared__ float  traj[N + 1][16];
    __shared__ float4 ex[2][16];     // [buf][sample] = partials {w0,w1,w2,w3}

    // ---- stage per-step inputs, coalesced ----
#pragma unroll
    for (int k = 0; k < 8; ++k) {
        const int f  = tid + 256 * k;       // < 2048
        const int ss = f >> 7;
        const int ii = f & 127;
        if (ii < N) {
            const size_t r = (size_t)(b0 + ss);
            const float vb = bm[r * N + ii];
            const float c0 = cn[r * (N + 1) + ii];
            const float c1 = cn[r * (N + 1) + ii + 1];
            const float vx = mx[r * (N + 1) + ii];
            const float vc = mc[r * N + ii];
            SI[ii][ss] = make_float4(vb, c1 - c0, vx, vc);
        }
    }

    // ---- this wave's MLP parameter set ----
    const float* W1 = mlp ? wc1 : w1;
    const float* B1 = mlp ? bc1 : b1;
    const float* W2 = mlp ? wc2 : w2;
    const float* B2 = mlp ? bc2 : b2;
    const float* W3 = mlp ? wc3 : w3;
    const float* B3 = mlp ? bc3 : b3;
    const float* alpha = ws + (mlp ? 10 : 0);
    const float* beta  = ws + (mlp ? 15 : 5);

    // ---- register-resident B-fragments of W2 (hi/lo), this wave's 2 nt ----
    short8 Bh[2][2], Bl[2][2];
#pragma unroll
    for (int kt = 0; kt < 2; ++kt) {
#pragma unroll
        for (int ntl = 0; ntl < 2; ++ntl) {
            const int nt = 2 * half + ntl;
            short8 fh, fl;
#pragma unroll
            for (int e = 0; e < 8; ++e) {
                short hi, lo;
                bf16_split(W2[(32 * kt + 8 * g + e) * 64 + 16 * nt + s], hi, lo);
                fh[e] = hi; fl[e] = lo;
            }
            Bh[kt][ntl] = fh; Bl[kt][ntl] = fl;
        }
    }

    // ---- bn affine for this lane's sample, layer-1 constants ----
    float bnv[IN_DIM];
    {
        const float* tvp = typeVec + (size_t)(b0 + s) * IN_DIM;
#pragma unroll
        for (int k = 0; k < IN_DIM; ++k)
            bnv[k] = fmaf(tvp[k], alpha[k], beta[k]);
    }
    float bs[16], wt[16], wx[16], wm[16], wcr[16];
#pragma unroll
    for (int j = 0; j < 16; ++j) {
        const int u = (j < 8) ? (g * 8 + j) : (32 + g * 8 + (j - 8));
        wt[j]  = W1[5 * 64 + u];
        wx[j]  = W1[6 * 64 + u];
        wm[j]  = W1[7 * 64 + u];
        wcr[j] = W1[8 * 64 + u];
        float a = B1[u];
#pragma unroll
        for (int k = 0; k < IN_DIM; ++k) a = fmaf(bnv[k], W1[k * 64 + u], a);
        bs[j] = a;
    }
    float b2v[2], w3v[2];
#pragma unroll
    for (int ntl = 0; ntl < 2; ++ntl) {
        const int nt = 2 * half + ntl;
        b2v[ntl] = B2[16 * nt + s];
        w3v[ntl] = W3[16 * nt + s];
    }
    const float b3s = B3[0];
    const float x0  = initial[0];

    float x = x0;
    if (tid < 16) traj[0][tid] = x0;
    __syncthreads();

    for (int i = 0; i < N; ++i) {
        const float t = (float)i * DT;
        const float4 in = SI[i][s];   // {bm, dcn, mx, mc}

        // ---- layer-1: 16 units in-lane, relu, hi/lo split to A-frags ----
        short8 ah0, ah1, al0, al1;
#pragma unroll
        for (int j = 0; j < 16; ++j) {
            float h = bs[j];
            h = fmaf(t,    wt[j],  h);
            h = fmaf(x,    wx[j],  h);
            h = fmaf(in.z, wm[j],  h);
            h = fmaf(in.w, wcr[j], h);
            h = fmaxf(h, 0.0f);
            short hi, lo;
            bf16_split(h, hi, lo);
            if (j < 8) { ah0[j] = hi; al0[j] = lo; }
            else       { ah1[j - 8] = hi; al1[j - 8] = lo; }
        }

        // ---- layer-2 MFMA: two 3-deep chains per ntl (split by kt) ----
        f32x4 acc0[2], acc1[2];
#pragma unroll
        for (int ntl = 0; ntl < 2; ++ntl) {
            acc0[ntl] = (f32x4){b2v[ntl], b2v[ntl], b2v[ntl], b2v[ntl]};
            acc1[ntl] = (f32x4){0.f, 0.f, 0.f, 0.f};
        }
#pragma unroll
        for (int ntl = 0; ntl < 2; ++ntl) {
            acc0[ntl] = __builtin_amdgcn_mfma_f32_16x16x32_bf16(ah0, Bh[0][ntl], acc0[ntl], 0, 0, 0);
            acc0[ntl] = __builtin_amdgcn_mfma_f32_16x16x32_bf16(al0, Bh[0][ntl], acc0[ntl], 0, 0, 0);
            acc0[ntl] = __builtin_amdgcn_mfma_f32_16x16x32_bf16(ah0, Bl[0][ntl], acc0[ntl], 0, 0, 0);
            acc1[ntl] = __builtin_amdgcn_mfma_f32_16x16x32_bf16(ah1, Bh[1][ntl], acc1[ntl], 0, 0, 0);
            acc1[ntl] = __builtin_amdgcn_mfma_f32_16x16x32_bf16(al1, Bh[1][ntl], acc1[ntl], 0, 0, 0);
            acc1[ntl] = __builtin_amdgcn_mfma_f32_16x16x32_bf16(ah1, Bl[1][ntl], acc1[ntl], 0, 0, 0);
        }

        // ---- layer-3 partial: relu * w3, DPP-reduce over 16 unit-lanes ----
        float r0 = 0.f, r1 = 0.f, r2 = 0.f, r3 = 0.f;
#pragma unroll
        for (int ntl = 0; ntl < 2; ++ntl) {
            const f32x4 fs = acc0[ntl] + acc1[ntl];
            r0 = fmaf(fmaxf(fs[0], 0.f), w3v[ntl], r0);
            r1 = fmaf(fmaxf(fs[1], 0.f), w3v[ntl], r1);
            r2 = fmaf(fmaxf(fs[2], 0.f), w3v[ntl], r2);
            r3 = fmaf(fmaxf(fs[3], 0.f), w3v[ntl], r3);
        }
        r0 = red16(r0); r1 = red16(r1); r2 = red16(r2); r3 = red16(r3);

        // lanes r4<4 of each g own sample 4g+r4; publish this wave's partial
        const int r4 = l & 15;
        float wv = r0;
        wv = (r4 == 1) ? r1 : wv;
        wv = (r4 == 2) ? r2 : wv;
        wv = (r4 == 3) ? r3 : wv;
        if (half == 0) wv += b3s;    // bias counted once per MLP
        if (r4 < 4) ((float*)&ex[i & 1][4 * g + r4])[wid] = wv;
        __syncthreads();

        // ---- merge partials, SDE update (redundant in all 4 waves) ----
        const float4 pv = ex[i & 1][s];   // {pi_h0, cl_h0, pi_h1, cl_h1}
        const float pi_v = pv.x + pv.z;
        const float c_v  = expf(pv.y + pv.w);
        const float drift = MU_DT + fmaf(NU, in.x, SIGMA * in.y);
        float xn = x + pi_v * x * drift - c_v * x * DT;
        xn = fmaxf(xn - FLOORV, 0.0f) + FLOORV;
        x = xn;

        if (tid < 16) traj[i + 1][tid] = x;
    }
    __syncthreads();

    // ---- epilogue: coalesced output write {t, x} ----
    const int TOT = 16 * (N + 1) * 2;            // 3232
#pragma unroll
    for (int k = 0; k < 13; ++k) {
        const int e = tid + 256 * k;
        if (e < TOT) {
            const int sample = e / (2 * (N + 1));
            const int r      = e - sample * (2 * (N + 1));
            const int i      = r >> 1;
            const float v    = (r & 1) ? traj[i][sample] : (float)i * DT;
            out[(size_t)b0 * (2 * (N + 1)) + e] = v;
        }
    }
}

extern "C" void kernel_launch(void* const* d_in, const int* in_sizes, int n_in,
                              void* d_out, int out_size, void* d_ws, size_t ws_size,
                              hipStream_t stream) {
    const float* bm        = (const float*)d_in[0];
    const float* cn        = (const float*)d_in[1];
    const float* typeVec   = (const float*)d_in[2];
    const float* mx        = (const float*)d_in[3];
    const float* mc        = (const float*)d_in[4];
    const float* initial   = (const float*)d_in[5];
    const float* bn_gamma  = (const float*)d_in[6];
    const float* bn_beta   = (const float*)d_in[7];
    const float* bnc_gamma = (const float*)d_in[8];
    const float* bnc_beta  = (const float*)d_in[9];
    const float* w1  = (const float*)d_in[10];
    const float* b1  = (const float*)d_in[11];
    const float* w2  = (const float*)d_in[12];
    const float* b2  = (const float*)d_in[13];
    const float* w3  = (const float*)d_in[14];
    const float* b3  = (const float*)d_in[15];
    const float* wc1 = (const float*)d_in[16];
    const float* bc1 = (const float*)d_in[17];
    const float* wc2 = (const float*)d_in[18];
    const float* bc2 = (const float*)d_in[19];
    const float* wc3 = (const float*)d_in[20];
    const float* bc3 = (const float*)d_in[21];
    float* wsp = (float*)d_ws;
    float* out = (float*)d_out;

    bn_stats_kernel<<<1, 1024, 0, stream>>>(typeVec, bn_gamma, bn_beta,
                                            bnc_gamma, bnc_beta, wsp);
    sim_kernel<<<512, 256, 0, stream>>>(bm, cn, typeVec, mx, mc, initial,
                                        w1, b1, w2, b2, w3, b3,
                                        wc1, bc1, wc2, bc2, wc3, bc3,
                                        wsp, out);
}

// Round 5
// 84.546 us; speedup vs baseline: 4.9598x; 1.1519x over previous
//
#include <hip/hip_runtime.h>
#include <math.h>

#define IN_DIM 5
constexpr int B = 8192;
constexpr int N = 100;
constexpr float DT     = 0.01f;
constexpr float MU_DT  = 0.001f;
constexpr float NU     = 0.2f;
constexpr float SIGMA  = 0.3f;
constexpr float BN_EPS = 1e-5f;
constexpr float FLOORV = 1e-4f;

typedef __attribute__((ext_vector_type(8))) short short8;
typedef __attribute__((ext_vector_type(4))) float f32x4;

// truncation-based bf16 split: h = hi + lo with |err| ~ 2^-16 |h|
__device__ __forceinline__ void bf16_split(float h, short& hi, short& lo) {
    unsigned int ub = __builtin_bit_cast(unsigned int, h);
    hi = (short)(ub >> 16);
    float hif = __builtin_bit_cast(float, ub & 0xffff0000u);
    float l = h - hif;
    lo = (short)(__builtin_bit_cast(unsigned int, l) >> 16);
}

// sum over each aligned 16-lane group via DPP (VALU only, no DS pipe)
__device__ __forceinline__ float red16(float v) {
#if __has_builtin(__builtin_amdgcn_update_dpp)
    int x;
    x = __builtin_amdgcn_update_dpp(0, __builtin_bit_cast(int, v), 0xB1, 0xF, 0xF, false);
    v += __builtin_bit_cast(float, x);
    x = __builtin_amdgcn_update_dpp(0, __builtin_bit_cast(int, v), 0x4E, 0xF, 0xF, false);
    v += __builtin_bit_cast(float, x);
    x = __builtin_amdgcn_update_dpp(0, __builtin_bit_cast(int, v), 0x141, 0xF, 0xF, false);
    v += __builtin_bit_cast(float, x);
    x = __builtin_amdgcn_update_dpp(0, __builtin_bit_cast(int, v), 0x140, 0xF, 0xF, false);
    v += __builtin_bit_cast(float, x);
    return v;
#else
    v += __shfl_xor(v, 1);
    v += __shfl_xor(v, 2);
    v += __shfl_xor(v, 4);
    v += __shfl_xor(v, 8);
    return v;
#endif
}

// ---------------------------------------------------------------------------
// Kernel 1: batch-norm stats (unchanged).
// ws[0..4]=alpha, ws[5..9]=beta', ws[10..14]=alphac, ws[15..19]=betac'
// ---------------------------------------------------------------------------
__global__ __launch_bounds__(1024) void bn_stats_kernel(
    const float* __restrict__ tv,
    const float* __restrict__ g1, const float* __restrict__ be1,
    const float* __restrict__ g2, const float* __restrict__ be2,
    float* __restrict__ ws)
{
    const int t = threadIdx.x;
    float s[IN_DIM] = {0.f, 0.f, 0.f, 0.f, 0.f};
    float q[IN_DIM] = {0.f, 0.f, 0.f, 0.f, 0.f};
    for (int r = t; r < B; r += 1024) {
        const float* row = tv + r * IN_DIM;
#pragma unroll
        for (int k = 0; k < IN_DIM; ++k) {
            const float v = row[k];
            s[k] += v;
            q[k] += v * v;
        }
    }
#pragma unroll
    for (int k = 0; k < IN_DIM; ++k) {
#pragma unroll
        for (int off = 32; off >= 1; off >>= 1) {
            s[k] += __shfl_xor(s[k], off);
            q[k] += __shfl_xor(q[k], off);
        }
    }
    __shared__ float red[16][2 * IN_DIM];
    const int w = t >> 6, lane = t & 63;
    if (lane == 0) {
#pragma unroll
        for (int k = 0; k < IN_DIM; ++k) {
            red[w][k] = s[k];
            red[w][IN_DIM + k] = q[k];
        }
    }
    __syncthreads();
    if (t == 0) {
#pragma unroll
        for (int k = 0; k < IN_DIM; ++k) {
            float S = 0.f, Q = 0.f;
            for (int u = 0; u < 16; ++u) { S += red[u][k]; Q += red[u][IN_DIM + k]; }
            const float mean = S / (float)B;
            const float var  = Q / (float)B - mean * mean;
            const float inv  = 1.0f / sqrtf(var + BN_EPS);
            const float a1 = inv * g1[k];
            const float a2 = inv * g2[k];
            ws[k]          = a1;
            ws[IN_DIM + k] = be1[k] - mean * a1;
            ws[10 + k]     = a2;
            ws[15 + k]     = be2[k] - mean * a2;
        }
    }
}

// ---------------------------------------------------------------------------
// Kernel 2: simulation. Block = 256 thr = 4 waves over the SAME 16 samples.
// wave w: mlp = w&1 (pi / c), q = w>>1.  Roles of q:
//   - layer-1: compute ONLY k-units u = 32q+8g+j (j<8) — no duplication;
//     hi/lo A-frags exchanged with the partner wave through LDS (barrier A).
//   - layer-2/3: output columns nt in {2q, 2q+1} (partials merged via `ex`,
//     barrier B). B-frags preloaded per-role: BhO/BlO pair with own A-frags
//     (kt=q), BhX/BlX with the exchanged frags (kt=1-q) — no runtime selects.
// All per-step inputs pre-staged in LDS; trajectory kept in LDS, coalesced
// epilogue write. Zero global ops inside the loop. Fast __expf.
// ---------------------------------------------------------------------------
__global__ __launch_bounds__(256, 2) void sim_kernel(
    const float* __restrict__ bm, const float* __restrict__ cn,
    const float* __restrict__ typeVec,
    const float* __restrict__ mx, const float* __restrict__ mc,
    const float* __restrict__ initial,
    const float* __restrict__ w1, const float* __restrict__ b1,
    const float* __restrict__ w2, const float* __restrict__ b2,
    const float* __restrict__ w3, const float* __restrict__ b3,
    const float* __restrict__ wc1, const float* __restrict__ bc1,
    const float* __restrict__ wc2, const float* __restrict__ bc2,
    const float* __restrict__ wc3, const float* __restrict__ bc3,
    const float* __restrict__ ws, float* __restrict__ out)
{
    const int tid = threadIdx.x;
    const int wid = tid >> 6;        // 0..3
    const int l   = tid & 63;
    const int s   = l & 15;          // sample (A-row) / unit-col index
    const int g   = l >> 4;          // k-octet / D-row group
    const int mlp = wid & 1;         // 0 = pi-MLP, 1 = c-MLP
    const int q   = wid >> 1;        // k-half (layer-1) and nt-half (layer-2/3)
    const int b0  = blockIdx.x * 16;

    __shared__ float4 SI[N][16];       // [step][sample] = {bm, dcn, mx, mc}
    __shared__ float  traj[N + 1][16];
    __shared__ float4 ex[16];          // [sample] = partials {w0,w1,w2,w3}
    __shared__ short8 FX[2][2][2][64]; // [mlp][q][hi/lo][lane] A-frag exchange

    // ---- stage per-step inputs, coalesced ----
#pragma unroll
    for (int k = 0; k < 8; ++k) {
        const int f  = tid + 256 * k;       // < 2048
        const int ss = f >> 7;
        const int ii = f & 127;
        if (ii < N) {
            const size_t r = (size_t)(b0 + ss);
            const float vb = bm[r * N + ii];
            const float c0 = cn[r * (N + 1) + ii];
            const float c1 = cn[r * (N + 1) + ii + 1];
            const float vx = mx[r * (N + 1) + ii];
            const float vc = mc[r * N + ii];
            SI[ii][ss] = make_float4(vb, c1 - c0, vx, vc);
        }
    }

    // ---- this wave's MLP parameter set ----
    const float* W1 = mlp ? wc1 : w1;
    const float* B1 = mlp ? bc1 : b1;
    const float* W2 = mlp ? wc2 : w2;
    const float* B2 = mlp ? bc2 : b2;
    const float* W3 = mlp ? wc3 : w3;
    const float* B3 = mlp ? bc3 : b3;
    const float* alpha = ws + (mlp ? 10 : 0);
    const float* beta  = ws + (mlp ? 15 : 5);

    // ---- B-fragments of W2 (hi/lo), per-role: O = kt=q, X = kt=1-q ----
    short8 BhO[2], BlO[2], BhX[2], BlX[2];
#pragma unroll
    for (int ntl = 0; ntl < 2; ++ntl) {
        const int nt = 2 * q + ntl;
        short8 fhO, flO, fhX, flX;
#pragma unroll
        for (int e = 0; e < 8; ++e) {
            short hi, lo;
            bf16_split(W2[(32 * q + 8 * g + e) * 64 + 16 * nt + s], hi, lo);
            fhO[e] = hi; flO[e] = lo;
            bf16_split(W2[(32 * (1 - q) + 8 * g + e) * 64 + 16 * nt + s], hi, lo);
            fhX[e] = hi; flX[e] = lo;
        }
        BhO[ntl] = fhO; BlO[ntl] = flO;
        BhX[ntl] = fhX; BlX[ntl] = flX;
    }

    // ---- bn affine for this lane's sample; layer-1 consts (8 units only) ----
    float bnv[IN_DIM];
    {
        const float* tvp = typeVec + (size_t)(b0 + s) * IN_DIM;
#pragma unroll
        for (int k = 0; k < IN_DIM; ++k)
            bnv[k] = fmaf(tvp[k], alpha[k], beta[k]);
    }
    float bs[8], wt[8], wx[8], wm[8], wcr[8];
#pragma unroll
    for (int j = 0; j < 8; ++j) {
        const int u = 32 * q + 8 * g + j;
        wt[j]  = W1[5 * 64 + u];
        wx[j]  = W1[6 * 64 + u];
        wm[j]  = W1[7 * 64 + u];
        wcr[j] = W1[8 * 64 + u];
        float a = B1[u];
#pragma unroll
        for (int k = 0; k < IN_DIM; ++k) a = fmaf(bnv[k], W1[k * 64 + u], a);
        bs[j] = a;
    }
    float b2v[2], w3v[2];
#pragma unroll
    for (int ntl = 0; ntl < 2; ++ntl) {
        const int nt = 2 * q + ntl;
        b2v[ntl] = B2[16 * nt + s];
        w3v[ntl] = W3[16 * nt + s];
    }
    const float b3s = B3[0];
    const float x0  = initial[0];

    float x = x0;
    if (tid < 16) traj[0][tid] = x0;
    __syncthreads();

    for (int i = 0; i < N; ++i) {
        const float t = (float)i * DT;
        const float4 in = SI[i][s];   // {bm, dcn, mx, mc}

        // ---- layer-1: 8 own k-units, relu, hi/lo split ----
        short8 oh, ol;
#pragma unroll
        for (int j = 0; j < 8; ++j) {
            float h = bs[j];
            h = fmaf(t,    wt[j],  h);
            h = fmaf(x,    wx[j],  h);
            h = fmaf(in.z, wm[j],  h);
            h = fmaf(in.w, wcr[j], h);
            h = fmaxf(h, 0.0f);
            short hi, lo;
            bf16_split(h, hi, lo);
            oh[j] = hi; ol[j] = lo;
        }
        // exchange A-frags with partner wave (same mlp, other q)
        FX[mlp][q][0][l] = oh;
        FX[mlp][q][1][l] = ol;
        __syncthreads();                       // barrier A
        const short8 xh = FX[mlp][1 - q][0][l];
        const short8 xl = FX[mlp][1 - q][1][l];

        // ---- layer-2 MFMA: two 3-deep chains per ntl (own-kt / other-kt) ----
        f32x4 acc0[2], acc1[2];
#pragma unroll
        for (int ntl = 0; ntl < 2; ++ntl) {
            acc0[ntl] = (f32x4){b2v[ntl], b2v[ntl], b2v[ntl], b2v[ntl]};
            acc1[ntl] = (f32x4){0.f, 0.f, 0.f, 0.f};
        }
#pragma unroll
        for (int ntl = 0; ntl < 2; ++ntl) {
            acc0[ntl] = __builtin_amdgcn_mfma_f32_16x16x32_bf16(oh, BhO[ntl], acc0[ntl], 0, 0, 0);
            acc0[ntl] = __builtin_amdgcn_mfma_f32_16x16x32_bf16(ol, BhO[ntl], acc0[ntl], 0, 0, 0);
            acc0[ntl] = __builtin_amdgcn_mfma_f32_16x16x32_bf16(oh, BlO[ntl], acc0[ntl], 0, 0, 0);
            acc1[ntl] = __builtin_amdgcn_mfma_f32_16x16x32_bf16(xh, BhX[ntl], acc1[ntl], 0, 0, 0);
            acc1[ntl] = __builtin_amdgcn_mfma_f32_16x16x32_bf16(xl, BhX[ntl], acc1[ntl], 0, 0, 0);
            acc1[ntl] = __builtin_amdgcn_mfma_f32_16x16x32_bf16(xh, BlX[ntl], acc1[ntl], 0, 0, 0);
        }

        // ---- layer-3 partial: relu * w3, DPP-reduce over 16 unit-lanes ----
        float r0 = 0.f, r1 = 0.f, r2 = 0.f, r3 = 0.f;
#pragma unroll
        for (int ntl = 0; ntl < 2; ++ntl) {
            const f32x4 fs = acc0[ntl] + acc1[ntl];
            r0 = fmaf(fmaxf(fs[0], 0.f), w3v[ntl], r0);
            r1 = fmaf(fmaxf(fs[1], 0.f), w3v[ntl], r1);
            r2 = fmaf(fmaxf(fs[2], 0.f), w3v[ntl], r2);
            r3 = fmaf(fmaxf(fs[3], 0.f), w3v[ntl], r3);
        }
        r0 = red16(r0); r1 = red16(r1); r2 = red16(r2); r3 = red16(r3);

        // lanes r4<4 of each g own sample 4g+r4; publish this wave's partial
        const int r4 = l & 15;
        float wv = r0;
        wv = (r4 == 1) ? r1 : wv;
        wv = (r4 == 2) ? r2 : wv;
        wv = (r4 == 3) ? r3 : wv;
        if (q == 0) wv += b3s;    // bias counted once per MLP
        if (r4 < 4) ((float*)&ex[4 * g + r4])[wid] = wv;
        __syncthreads();                       // barrier B

        // ---- merge partials, SDE update (redundant in all 4 waves) ----
        const float4 pv = ex[s];   // {pi_q0, cl_q0, pi_q1, cl_q1}
        const float pi_v = pv.x + pv.z;
        const float c_v  = __expf(pv.y + pv.w);
        const float drift = MU_DT + fmaf(NU, in.x, SIGMA * in.y);
        float xn = x + pi_v * x * drift - c_v * x * DT;
        xn = fmaxf(xn - FLOORV, 0.0f) + FLOORV;
        x = xn;

        if (tid < 16) traj[i + 1][tid] = x;
    }
    __syncthreads();

    // ---- epilogue: coalesced output write {t, x} ----
    const int TOT = 16 * (N + 1) * 2;            // 3232
#pragma unroll
    for (int k = 0; k < 13; ++k) {
        const int e = tid + 256 * k;
        if (e < TOT) {
            const int sample = e / (2 * (N + 1));
            const int r      = e - sample * (2 * (N + 1));
            const int i      = r >> 1;
            const float v    = (r & 1) ? traj[i][sample] : (float)i * DT;
            out[(size_t)b0 * (2 * (N + 1)) + e] = v;
        }
    }
}

extern "C" void kernel_launch(void* const* d_in, const int* in_sizes, int n_in,
                              void* d_out, int out_size, void* d_ws, size_t ws_size,
                              hipStream_t stream) {
    const float* bm        = (const float*)d_in[0];
    const float* cn        = (const float*)d_in[1];
    const float* typeVec   = (const float*)d_in[2];
    const float* mx        = (const float*)d_in[3];
    const float* mc        = (const float*)d_in[4];
    const float* initial   = (const float*)d_in[5];
    const float* bn_gamma  = (const float*)d_in[6];
    const float* bn_beta   = (const float*)d_in[7];
    const float* bnc_gamma = (const float*)d_in[8];
    const float* bnc_beta  = (const float*)d_in[9];
    const float* w1  = (const float*)d_in[10];
    const float* b1  = (const float*)d_in[11];
    const float* w2  = (const float*)d_in[12];
    const float* b2  = (const float*)d_in[13];
    const float* w3  = (const float*)d_in[14];
    const float* b3  = (const float*)d_in[15];
    const float* wc1 = (const float*)d_in[16];
    const float* bc1 = (const float*)d_in[17];
    const float* wc2 = (const float*)d_in[18];
    const float* bc2 = (const float*)d_in[19];
    const float* wc3 = (const float*)d_in[20];
    const float* bc3 = (const float*)d_in[21];
    float* wsp = (float*)d_ws;
    float* out = (float*)d_out;

    bn_stats_kernel<<<1, 1024, 0, stream>>>(typeVec, bn_gamma, bn_beta,
                                            bnc_gamma, bnc_beta, wsp);
    sim_kernel<<<512, 256, 0, stream>>>(bm, cn, typeVec, mx, mc, initial,
                                        w1, b1, w2, b2, w3, b3,
                                        wc1, bc1, wc2, bc2, wc3, bc3,
                                        wsp, out);
}